// Round 6
// baseline (449.028 us; speedup 1.0000x reference)
//
#include <hip/hip_runtime.h>
#include <stdint.h>

#define HEADS 16
#define NTOK 98
#define HD 32
#define SCALE_Q 0.17677669529663687f

typedef __attribute__((ext_vector_type(4))) float floatx4;
typedef __attribute__((ext_vector_type(8))) short shortx8;

__device__ __forceinline__ unsigned short f2bf(float f) {
  union { float f; unsigned u; } v; v.f = f;
  unsigned r = v.u + 0x7fffu + ((v.u >> 16) & 1u);
  return (unsigned short)(r >> 16);
}
__device__ __forceinline__ float bf2f(unsigned short s) {
  union { unsigned u; float f; } v; v.u = ((unsigned)s) << 16;
  return v.f;
}

__device__ __forceinline__ void gload_lds16(const void* g, void* l) {
  __builtin_amdgcn_global_load_lds(
      (const __attribute__((address_space(1))) unsigned int*)g,
      (__attribute__((address_space(3))) unsigned int*)l, 16, 0, 0);
}

// ---------------- fused prep kernel ----------------
// blocks [0,12544): convert x -> bf16
// blocks [12544,15616): convert qkv_w / proj_w -> bf16
// blocks [15616,20096): build fragment-ordered bf16 bias/mask tables
//   biasF[h][mt][lane][e]  16*7*64*32 shorts, maskF[w][mt][lane][e] 64*7*64*32
//   e = nt*4+r (pad to 32); i = mt*16+(lane>>4)*4+r; j = nt*16+(lane&15)
//   mask pad: j>=98 -> -1e30 (kills softmax); rows i>=98 discarded at store.
__global__ void prep_kernel(const float* __restrict__ x,
                            const float* __restrict__ qkv_w,
                            const float* __restrict__ proj_w,
                            const float* __restrict__ table,
                            const int* __restrict__ rel,
                            const float* __restrict__ mask,
                            unsigned short* __restrict__ xbf,
                            unsigned short* __restrict__ wq,
                            unsigned short* __restrict__ wp,
                            unsigned short* __restrict__ biasF,
                            unsigned short* __restrict__ maskF) {
  const int bid = blockIdx.x, tid = threadIdx.x;
  if (bid < 12544) {
    int idx = bid * 256 + tid;  // one per 8 elems; 3,211,264 total
    const float4 f0 = *(const float4*)(x + (size_t)idx * 8);
    const float4 f1 = *(const float4*)(x + (size_t)idx * 8 + 4);
    union { ushort us[8]; uint4 u4; } pk;
    pk.us[0] = f2bf(f0.x); pk.us[1] = f2bf(f0.y);
    pk.us[2] = f2bf(f0.z); pk.us[3] = f2bf(f0.w);
    pk.us[4] = f2bf(f1.x); pk.us[5] = f2bf(f1.y);
    pk.us[6] = f2bf(f1.z); pk.us[7] = f2bf(f1.w);
    *(uint4*)(xbf + (size_t)idx * 8) = pk.u4;
  } else if (bid < 15616) {
    int idx = (bid - 12544) * 256 + tid;
    if (idx < 1536 * 512) wq[idx] = f2bf(qkv_w[idx]);
    if (idx < 512 * 512) wp[idx] = f2bf(proj_w[idx]);
  } else {
    int idx = (bid - 15616) * 256 + tid;  // 1,146,880 total
    if (idx < 229376) {
      int e = idx & 31, lane = (idx >> 5) & 63;
      int rest = idx >> 11;          // h*7 + mt
      int mt = rest % 7, h = rest / 7;
      int nt = e >> 2, r = e & 3;
      int i = mt * 16 + ((lane >> 4) << 2) + r;
      int j = (nt << 4) + (lane & 15);
      int ii = i < NTOK ? i : 97, jj = j < NTOK ? j : 97;
      float v = (nt < 7) ? table[rel[ii * NTOK + jj] * HEADS + h] : 0.f;
      biasF[idx] = f2bf(v);
    } else {
      int t = idx - 229376;
      int e = t & 31, lane = (t >> 5) & 63;
      int rest = t >> 11;            // w*7 + mt
      int mt = rest % 7, wdx = rest / 7;
      int nt = e >> 2, r = e & 3;
      int i = mt * 16 + ((lane >> 4) << 2) + r;
      int j = (nt << 4) + (lane & 15);
      float v;
      if (nt >= 7) v = 0.f;
      else if (j >= NTOK) v = -1e30f;
      else {
        int ii = i < NTOK ? i : 97;
        v = mask[wdx * (NTOK * NTOK) + ii * NTOK + j];
      }
      maskF[t] = f2bf(v);
    }
  }
}

// ---------------- QKV GEMM: C[50176,1536] = xbf[50176,512] @ qkv_w[1536,512]^T ----------------
// 128x256 tile, BK=32, 256 threads = 4 waves (2x2), each wave 64x128 (acc 4x8).
// Rationale: LDS-read-bound at 64x64 wave tiles (0.5 reads/MFMA, MfmaUtil 31%
// == LDS-port model); 64x128 cuts per-CU LDS reads 25% (0.375 reads/MFMA).
// 1D grid with bijective XCD swizzle keeps the A-panel L2-hot (FETCH 54 MB).
// 3-buffer pipeline, counted vmcnt(6) (6 loads/stage), drain-0 only last iter.
__global__ __launch_bounds__(256, 2)
void qkv_gemm_kernel(const unsigned short* __restrict__ xbf,
                     const unsigned short* __restrict__ wbf,
                     const float* __restrict__ qkv_b,
                     unsigned short* __restrict__ q_out,
                     unsigned short* __restrict__ k_out,
                     unsigned short* __restrict__ v_out) {
  __shared__ unsigned short As[3][128 * 32];
  __shared__ unsigned short Bs[3][256 * 32];
  const int tid = threadIdx.x;
  const int wave = tid >> 6, lane = tid & 63;
  const int id = blockIdx.x;                // 2352 = 8 * (49*6)
  const int xc = id & 7, tt = id >> 3;
  const int m0 = (xc * 49 + tt / 6) * 128, n0 = (tt % 6) * 256;
  const int wm = wave & 1, wn = wave >> 1;  // 2x2 wave grid
  const int ln15 = lane & 15, qd = lane >> 4;
  const int bl_r = lane >> 2, bl_s = lane & 3;

  const int sg_st = bl_s ^ ((bl_r >> 1) & 3);       // staging source seg
  const int swz_rd = (qd ^ ((ln15 >> 1) & 3)) * 8;  // read seg offset (shorts)

  const unsigned short* aG0 = xbf + (size_t)(m0 + wave * 16 + bl_r) * 512 + sg_st * 8;
  const unsigned short* aG1 = aG0 + (size_t)64 * 512;
  const unsigned short* bG0 = wbf + (size_t)(n0 + wave * 16 + bl_r) * 512 + sg_st * 8;

#define QSTAGE(bufi, kk)                                                          \
  do {                                                                            \
    gload_lds16((const void*)(aG0 + (kk)), (void*)&As[bufi][wave * 512]);         \
    gload_lds16((const void*)(aG1 + (kk)), (void*)&As[bufi][2048 + wave * 512]);  \
    gload_lds16((const void*)(bG0 + (kk)), (void*)&Bs[bufi][wave * 512]);         \
    gload_lds16((const void*)(bG0 + (size_t)64 * 512 + (kk)),                     \
                (void*)&Bs[bufi][2048 + wave * 512]);                             \
    gload_lds16((const void*)(bG0 + (size_t)128 * 512 + (kk)),                    \
                (void*)&Bs[bufi][4096 + wave * 512]);                             \
    gload_lds16((const void*)(bG0 + (size_t)192 * 512 + (kk)),                    \
                (void*)&Bs[bufi][6144 + wave * 512]);                             \
  } while (0)

  QSTAGE(0, 0);
  QSTAGE(1, 32);

  floatx4 acc[4][8] = {};
#pragma unroll
  for (int it = 0; it < 16; ++it) {
    if (it == 15) asm volatile("s_waitcnt vmcnt(0)" ::: "memory");
    else          asm volatile("s_waitcnt vmcnt(6)" ::: "memory");
    __builtin_amdgcn_sched_barrier(0);
    __builtin_amdgcn_s_barrier();
    __builtin_amdgcn_sched_barrier(0);
    if (it + 2 < 16) QSTAGE((it + 2) % 3, (it + 2) * 32);
    const unsigned short* Ab = As[it % 3];
    const unsigned short* Bb = Bs[it % 3];
    shortx8 afrag[4], bfrag[8];
#pragma unroll
    for (int mt = 0; mt < 4; ++mt)
      afrag[mt] = *(const shortx8*)&Ab[(wm * 64 + mt * 16 + ln15) * 32 + swz_rd];
#pragma unroll
    for (int nt = 0; nt < 8; ++nt)
      bfrag[nt] = *(const shortx8*)&Bb[(wn * 128 + nt * 16 + ln15) * 32 + swz_rd];
    __builtin_amdgcn_s_setprio(1);
#pragma unroll
    for (int mt = 0; mt < 4; ++mt)
#pragma unroll
      for (int nt = 0; nt < 8; ++nt)
        acc[mt][nt] = __builtin_amdgcn_mfma_f32_16x16x32_bf16(
            afrag[mt], bfrag[nt], acc[mt][nt], 0, 0, 0);
    __builtin_amdgcn_s_setprio(0);
  }
#undef QSTAGE

  // epilogue: + qkv_b, scale q, scatter to [B,H,98,32] bf16.
  // which-output is block-uniform (n0 multiple of 256, 512-wide buckets).
  const int which = n0 >> 9;
  unsigned short* __restrict__ outp =
      (which == 0) ? q_out : ((which == 1) ? k_out : v_out);
  const float sc = (which == 0) ? SCALE_Q : 1.0f;
#pragma unroll
  for (int mt = 0; mt < 4; ++mt) {
#pragma unroll
    for (int r = 0; r < 4; ++r) {
      int grow = m0 + wm * 64 + mt * 16 + qd * 4 + r;
      unsigned b = (unsigned)grow / 98u;
      unsigned i = (unsigned)grow - b * 98u;
#pragma unroll
      for (int nt = 0; nt < 8; ++nt) {
        int col = n0 + wn * 128 + nt * 16 + ln15;
        float val = (acc[mt][nt][r] + qkv_b[col]) * sc;
        int h = (col >> 5) & 15;
        int d = col & 31;
        size_t oidx = ((size_t)(b * 16 + h) * 98 + i) * 32 + d;
        outp[oidx] = f2bf(val);
      }
    }
  }
}

// ---------------- attention: one block per (b,h), 7 waves, one m-tile per wave ----------------
__global__ __launch_bounds__(448, 6)
void attn_kernel(const unsigned short* __restrict__ qg,
                 const unsigned short* __restrict__ kg,
                 const unsigned short* __restrict__ vg,
                 const unsigned short* __restrict__ biasF,
                 const unsigned short* __restrict__ maskF,
                 unsigned short* __restrict__ outg) {
  __shared__ __align__(16) unsigned short Vt[32 * 136];   // 8704 B
  __shared__ __align__(16) unsigned short Ps[7][1928];    // 16 rows x 120 + 8 pad, per wave
  const int tid = threadIdx.x;
  const int bh = blockIdx.x;
  const int b = bh >> 4, h = bh & 15, w = b & 63;
  const size_t base = (size_t)bh * (NTOK * HD);
  const int wave = tid >> 6, lane = tid & 63;   // wave = m-tile (0..6)
  const int ln15 = lane & 15, qd = lane >> 4;

  // zero Vt (pad cols 98..135) and Ps (pad cols 112..119 + tail) — all MFMA
  // slack reads must be finite zeros
  for (int idx = tid; idx < 544; idx += 448)
    ((uint4*)Vt)[idx] = make_uint4(0, 0, 0, 0);
  for (int idx = tid; idx < 1687; idx += 448)
    ((uint4*)Ps)[idx] = make_uint4(0, 0, 0, 0);
  __syncthreads();
  // transpose V into Vt[d][j]; seg-staggered write order spreads the 8-row
  // seg groups across bank quadrants
  for (int t = tid; t < 392; t += 448) {
    int i = t >> 2, seg = t & 3;
    union { uint4 u4; unsigned short us[8]; } u;
    u.u4 = *(const uint4*)(vg + base + i * 32 + seg * 8);
    int d0 = seg * 8;
#pragma unroll
    for (int e0 = 0; e0 < 8; ++e0) {
      int e = (e0 + seg * 2) & 7;
      Vt[(d0 + e) * 136 + i] = u.us[e];
    }
  }
  __syncthreads();

  const int mt = wave;
  // bf16 fragment-ordered bias/mask chunks (L2-resident, 8 x 16B per lane);
  // issued before QK^T so latency hides under the MFMAs
  const shortx8* bB = (const shortx8*)(biasF + (((size_t)h * 7 + mt) * 64 + lane) * 32);
  const shortx8* mB = (const shortx8*)(maskF + (((size_t)w * 7 + mt) * 64 + lane) * 32);
  shortx8 bias_c[4], mask_c[4];
#pragma unroll
  for (int c = 0; c < 4; ++c) { bias_c[c] = bB[c]; mask_c[c] = mB[c]; }

  shortx8 af = *(const shortx8*)(qg + base + (mt * 16 + ln15) * 32 + qd * 8);
  floatx4 sacc[7];
  __builtin_amdgcn_s_setprio(1);
#pragma unroll
  for (int nt = 0; nt < 7; ++nt) {
    shortx8 bf = *(const shortx8*)(kg + base + (nt * 16 + ln15) * 32 + qd * 8);
    floatx4 z = {};
    sacc[nt] = __builtin_amdgcn_mfma_f32_16x16x32_bf16(af, bf, z, 0, 0, 0);
  }
  __builtin_amdgcn_s_setprio(0);
  // add bias+mask (frees the chunks before softmax)
#pragma unroll
  for (int nt = 0; nt < 7; ++nt)
#pragma unroll
    for (int r = 0; r < 4; ++r) {
      int ee = nt * 4 + r, c = ee >> 3, el = ee & 7;
      sacc[nt][r] += bf2f((unsigned short)bias_c[c][el]) +
                     bf2f((unsigned short)mask_c[c][el]);
    }

  float linv[4];
#pragma unroll
  for (int r = 0; r < 4; ++r) {
    float mx = sacc[0][r];
#pragma unroll
    for (int nt = 1; nt < 7; ++nt) mx = fmaxf(mx, sacc[nt][r]);
#pragma unroll
    for (int off = 1; off < 16; off <<= 1)
      mx = fmaxf(mx, __shfl_xor(mx, off, 64));
    float sum = 0.f;
#pragma unroll
    for (int nt = 0; nt < 7; ++nt) {
      float p = __expf(sacc[nt][r] - mx);
      sacc[nt][r] = p;
      sum += p;
    }
#pragma unroll
    for (int off = 1; off < 16; off <<= 1) sum += __shfl_xor(sum, off, 64);
    linv[r] = 1.0f / sum;
  }

  // store full 16x112 P once (stride 120 shorts: 2-way max bank aliasing),
  // then 4 pipelined k-slice MFMAs — no per-slice write->read serialization
  unsigned short* Pw = Ps[wave];
#pragma unroll
  for (int nt = 0; nt < 7; ++nt)
#pragma unroll
    for (int r = 0; r < 4; ++r)
      Pw[(qd * 4 + r) * 120 + nt * 16 + ln15] = f2bf(sacc[nt][r]);

  floatx4 o0 = {}, o1 = {};
  __builtin_amdgcn_s_setprio(1);
#pragma unroll
  for (int ks = 0; ks < 4; ++ks) {
    shortx8 ap = *(const shortx8*)&Pw[ln15 * 120 + ks * 32 + qd * 8];
    shortx8 bv0 = *(const shortx8*)&Vt[ln15 * 136 + ks * 32 + qd * 8];
    shortx8 bv1 = *(const shortx8*)&Vt[(16 + ln15) * 136 + ks * 32 + qd * 8];
    o0 = __builtin_amdgcn_mfma_f32_16x16x32_bf16(ap, bv0, o0, 0, 0, 0);
    o1 = __builtin_amdgcn_mfma_f32_16x16x32_bf16(ap, bv1, o1, 0, 0, 0);
  }
  __builtin_amdgcn_s_setprio(0);
  // store this m-tile to [b*98+i][512] at col h*32
#pragma unroll
  for (int r = 0; r < 4; ++r) {
    int i = mt * 16 + qd * 4 + r;
    if (i < NTOK) {
      size_t ob = ((size_t)b * NTOK + i) * 512 + h * 32;
      outg[ob + ln15] = f2bf(o0[r] * linv[r]);
      outg[ob + 16 + ln15] = f2bf(o1[r] * linv[r]);
    }
  }
}

// ---------------- proj GEMM: out[50176,512] = attn[50176,512] @ proj_w[512,512]^T + b ----------------
// 128x128 tile, 256 threads (4 waves 2x2, each 64x64), 3 blocks/CU (48 KB LDS)
// -> grid 1568 = 2.04 occupancy rounds. 3-buffer counted vmcnt(4) + swizzles.
__global__ __launch_bounds__(256, 3)
void proj_gemm_kernel(const unsigned short* __restrict__ a,
                      const unsigned short* __restrict__ wbf,
                      const float* __restrict__ proj_b,
                      float* __restrict__ out) {
  __shared__ unsigned short As[3][128 * 32];
  __shared__ unsigned short Bs[3][128 * 32];
  const int tid = threadIdx.x;
  const int wave = tid >> 6, lane = tid & 63;
  const int id = blockIdx.x;                // 1568 = 8 * (49*4)
  const int xc = id & 7, tt = id >> 3;
  const int m0 = (xc * 49 + (tt >> 2)) * 128, n0 = (tt & 3) * 128;
  const int wm = wave & 1, wn = wave >> 1;
  const int ln15 = lane & 15, qd = lane >> 4;
  const int bl_r = lane >> 2, bl_s = lane & 3;

  const int sg_st = bl_s ^ ((bl_r >> 1) & 3);
  const int swz_rd = (qd ^ ((ln15 >> 1) & 3)) * 8;

  const unsigned short* aG0 = a + (size_t)(m0 + wave * 32 + bl_r) * 512 + sg_st * 8;
  const unsigned short* aG1 = aG0 + (size_t)16 * 512;
  const unsigned short* bG0 = wbf + (size_t)(n0 + wave * 32 + bl_r) * 512 + sg_st * 8;
  const unsigned short* bG1 = bG0 + (size_t)16 * 512;

#define PSTAGE(bufi, kk)                                                         \
  do {                                                                           \
    gload_lds16((const void*)(aG0 + (kk)), (void*)&As[bufi][wave * 1024]);       \
    gload_lds16((const void*)(aG1 + (kk)), (void*)&As[bufi][wave * 1024 + 512]); \
    gload_lds16((const void*)(bG0 + (kk)), (void*)&Bs[bufi][wave * 1024]);       \
    gload_lds16((const void*)(bG1 + (kk)), (void*)&Bs[bufi][wave * 1024 + 512]); \
  } while (0)

  PSTAGE(0, 0);
  PSTAGE(1, 32);

  floatx4 acc[4][4] = {};
#pragma unroll
  for (int it = 0; it < 16; ++it) {
    if (it == 15) asm volatile("s_waitcnt vmcnt(0)" ::: "memory");
    else          asm volatile("s_waitcnt vmcnt(4)" ::: "memory");
    __builtin_amdgcn_sched_barrier(0);
    __builtin_amdgcn_s_barrier();
    __builtin_amdgcn_sched_barrier(0);
    if (it + 2 < 16) PSTAGE((it + 2) % 3, (it + 2) * 32);
    const unsigned short* Ab = As[it % 3];
    const unsigned short* Bb = Bs[it % 3];
    shortx8 afrag[4], bfrag[4];
#pragma unroll
    for (int mt = 0; mt < 4; ++mt)
      afrag[mt] = *(const shortx8*)&Ab[(wm * 64 + mt * 16 + ln15) * 32 + swz_rd];
#pragma unroll
    for (int nt = 0; nt < 4; ++nt)
      bfrag[nt] = *(const shortx8*)&Bb[(wn * 64 + nt * 16 + ln15) * 32 + swz_rd];
    __builtin_amdgcn_s_setprio(1);
#pragma unroll
    for (int mt = 0; mt < 4; ++mt)
#pragma unroll
      for (int nt = 0; nt < 4; ++nt)
        acc[mt][nt] = __builtin_amdgcn_mfma_f32_16x16x32_bf16(
            afrag[mt], bfrag[nt], acc[mt][nt], 0, 0, 0);
    __builtin_amdgcn_s_setprio(0);
  }
#undef PSTAGE

#pragma unroll
  for (int mt = 0; mt < 4; ++mt) {
#pragma unroll
    for (int r = 0; r < 4; ++r) {
      int grow = m0 + wm * 64 + mt * 16 + qd * 4 + r;
#pragma unroll
      for (int nt = 0; nt < 4; ++nt) {
        int col = n0 + wn * 64 + nt * 16 + ln15;
        out[(size_t)grow * 512 + col] = acc[mt][nt][r] + proj_b[col];
      }
    }
  }
}

// ---------------- launch ----------------
extern "C" void kernel_launch(void* const* d_in, const int* in_sizes, int n_in,
                              void* d_out, int out_size, void* d_ws, size_t ws_size,
                              hipStream_t stream) {
  const float* x          = (const float*)d_in[0];
  const float* mask       = (const float*)d_in[1];
  const float* qkv_w      = (const float*)d_in[2];
  const float* qkv_b      = (const float*)d_in[3];
  const float* proj_w     = (const float*)d_in[4];
  const float* proj_b     = (const float*)d_in[5];
  const float* bias_table = (const float*)d_in[6];
  const int*   rel_index  = (const int*)d_in[7];
  float* out = (float*)d_out;

  char* ws = (char*)d_ws;
  unsigned short* ws_qkvw  = (unsigned short*)(ws + 0);           // 1,572,864
  unsigned short* ws_projw = (unsigned short*)(ws + 1572864);     //   524,288
  unsigned short* ws_biasF = (unsigned short*)(ws + 2097152);     //   458,752
  unsigned short* ws_maskF = (unsigned short*)(ws + 2555904);     // 1,835,008
  unsigned short* ws_q     = (unsigned short*)(ws + 4390912);     // 51,380,224
  unsigned short* ws_k     = (unsigned short*)(ws + 55771136);
  unsigned short* ws_v     = (unsigned short*)(ws + 107151360);
  unsigned short* ws_attn  = (unsigned short*)(ws + 158531584);   // end 209,911,808
  unsigned short* ws_xbf   = ws_attn;  // aliased: xbf dead before attn writes

  hipLaunchKernelGGL(prep_kernel, dim3(20096), dim3(256), 0, stream,
                     x, qkv_w, proj_w, bias_table, rel_index, mask,
                     ws_xbf, ws_qkvw, ws_projw, ws_biasF, ws_maskF);
  hipLaunchKernelGGL(qkv_gemm_kernel, dim3(2352), dim3(256), 0, stream,
                     ws_xbf, ws_qkvw, qkv_b, ws_q, ws_k, ws_v);
  hipLaunchKernelGGL(attn_kernel, dim3(8192), dim3(448), 0, stream,
                     ws_q, ws_k, ws_v, ws_biasF, ws_maskF, ws_attn);
  hipLaunchKernelGGL(proj_gemm_kernel, dim3(1568), dim3(256), 0, stream,
                     ws_attn, ws_projw, proj_b, out);
}